// Round 4
// baseline (201.326 us; speedup 1.0000x reference)
//
#include <hip/hip_runtime.h>
#include <hip/hip_bf16.h>

// Model_3315714753203: B=4,S=2048,I=512,D=512,H=8,HD=64,P=720.
// fp32 inputs (probed in convert) -> internal bf16.
// 5 dispatches: convert(+inline probe) -> qkv job-table GEMM -> flash v12 ->
// GEMM up -> GEMM out. ALL GEMM LDS tiles XOR-chunk-swizzled.
// flash v12 = v11 + amdgpu_waves_per_eu(4,4). v11 still spilled ~8MB/iter
// (WRITE 16.4 vs 8.4 ideal) because launch_bounds(512,4) only sets a MIN
// waves/EU: the allocator opportunistically targeted 8 waves/EU (64 VGPR)
// even though 64KB LDS caps residency at 2 blocks/CU = 4 waves/EU, so the
// 64-reg choice bought zero occupancy and paid pure spill. Pinning
// min=max=4 gives the allocator the full 128-reg budget (demand ~90-100).

typedef short bf16x8 __attribute__((ext_vector_type(8)));
typedef short short4v __attribute__((ext_vector_type(4)));
typedef float f32x4 __attribute__((ext_vector_type(4)));
typedef const __attribute__((address_space(1))) void* gptr_t;
typedef __attribute__((address_space(3))) void* sptr_t;

__device__ __forceinline__ f32x4 mfma16(bf16x8 a, bf16x8 b, f32x4 c) {
    return __builtin_amdgcn_mfma_f32_16x16x32_bf16(a, b, c, 0, 0, 0);
}
__device__ __forceinline__ f32x4 mfma16k(short4v a, short4v b, f32x4 c) {
#if __has_builtin(__builtin_amdgcn_mfma_f32_16x16x16bf16_1k)
    return __builtin_amdgcn_mfma_f32_16x16x16bf16_1k(a, b, c, 0, 0, 0);
#else
    (void)a; (void)b; return c;   // host-pass stub
#endif
}
__device__ __forceinline__ void async16(const void* g, void* l) {
    __builtin_amdgcn_global_load_lds((gptr_t)g, (sptr_t)l, 16, 0, 0);
}
// raw v_exp_f32 (OCML exp2f adds ~6 insts of fixup we don't need: scores bounded)
__device__ __forceinline__ float fexp2(float x) {
#if __has_builtin(__builtin_amdgcn_exp2f)
    return __builtin_amdgcn_exp2f(x);
#else
    return exp2f(x);
#endif
}
// pack 4 f32 -> 4 bf16 (round-half-up: +0x8000, take high 16)
__device__ __forceinline__ short4v pack_bf16x4(f32x4 v) {
    unsigned a = __builtin_bit_cast(unsigned, v[0]) + 0x8000u;
    unsigned b = __builtin_bit_cast(unsigned, v[1]) + 0x8000u;
    unsigned c = __builtin_bit_cast(unsigned, v[2]) + 0x8000u;
    unsigned d = __builtin_bit_cast(unsigned, v[3]) + 0x8000u;
    int2 t;
    t.x = (int)__builtin_amdgcn_perm(b, a, 0x07060302u);
    t.y = (int)__builtin_amdgcn_perm(d, c, 0x07060302u);
    return __builtin_bit_cast(short4v, t);
}

// ---------------- convert all inputs to bf16, inline dtype probe
struct CDesc { const void* s; __hip_bfloat16* d; int n; int mode; };
struct CTab  { CDesc t[11]; };

__global__ void convert_all(CTab tab, const unsigned* __restrict__ x0,
                            int* __restrict__ flag) {
    __shared__ int sflag;
    if (threadIdx.x < 64) {
        unsigned e = (x0[threadIdx.x] >> 23) & 0xffu;
        unsigned long long m = __ballot(e >= 100u && e <= 145u);
        if (threadIdx.x == 0) sflag = (__popcll(m) >= 32) ? 1 : 0;
    }
    __syncthreads();
    const int isF32 = sflag;
    if (blockIdx.x == 0 && blockIdx.y == 0 && threadIdx.x == 0) *flag = isF32;

    CDesc de = tab.t[blockIdx.y];
    for (int i = blockIdx.x * 256 + threadIdx.x; i < de.n; i += gridDim.x * 256) {
        int si = i;
        if (de.mode) {  // dst [h][d][i512] <- src [h][i512][d]
            int ii = i & 511, d = (i >> 9) & 63, h = i >> 15;
            si = (h * 512 + ii) * 64 + d;
        }
        float v = isF32 ? ((const float*)de.s)[si]
                        : (float)((const __hip_bfloat16*)de.s)[si];
        de.d[i] = __float2bfloat16(v);
    }
}

// ---------------- shared GEMM body (K=512), XOR-swizzled LDS tiles:
// staging puts global chunk kc^(row&7) in slot kc -> fragment read slot
// ((ks>>3)+lg)^(row&7) spreads over all 8 bank-groups (2-way max = free).
template<int BM, int BN>
__device__ __forceinline__ void gemm_body(
    const __hip_bfloat16* __restrict__ A,
    const __hip_bfloat16* __restrict__ B,
    __hip_bfloat16* __restrict__ C,
    int M, int N, int m0, int n0, int ldc,
    const __hip_bfloat16* biasM, const __hip_bfloat16* biasN, float csc,
    __hip_bfloat16* lA, __hip_bfloat16* lB)
{
    constexpr int FM = BM / 32, FN = BN / 32;
    const int tid = threadIdx.x, lane = tid & 63, wave = tid >> 6;
    const int wm = (wave >> 1) * (BM / 2), wn = (wave & 1) * (BN / 2);
    const int lc = lane & 15, lg = lane >> 4;

    f32x4 acc[FM][FN] = {};
    constexpr int CA = BM * 8 / 256, CB = BN * 8 / 256;

    for (int k0 = 0; k0 < 512; k0 += 64) {
        #pragma unroll
        for (int j = 0; j < CA; ++j) {
            int ch = j * 256 + tid;
            int m = ch >> 3, kc = (ch & 7) ^ (m & 7);
            int mg = m0 + m; if (mg > M - 1) mg = M - 1;
            async16(&A[(size_t)mg * 512 + k0 + kc * 8], &lA[ch * 8]);
        }
        #pragma unroll
        for (int j = 0; j < CB; ++j) {
            int ch = j * 256 + tid;
            int n = ch >> 3, kc = (ch & 7) ^ (n & 7);
            int ng = n0 + n; if (ng > N - 1) ng = N - 1;
            async16(&B[(size_t)ng * 512 + k0 + kc * 8], &lB[ch * 8]);
        }
        __syncthreads();
        #pragma unroll
        for (int ks = 0; ks < 64; ks += 32) {
            bf16x8 af[FM], bfr[FN];
            #pragma unroll
            for (int i = 0; i < FM; ++i) {
                int row = wm + i * 16 + lc;
                af[i] = *(const bf16x8*)&lA[row * 64 + (((ks >> 3) + lg) ^ (row & 7)) * 8];
            }
            #pragma unroll
            for (int j = 0; j < FN; ++j) {
                int row = wn + j * 16 + lc;
                bfr[j] = *(const bf16x8*)&lB[row * 64 + (((ks >> 3) + lg) ^ (row & 7)) * 8];
            }
            #pragma unroll
            for (int i = 0; i < FM; ++i)
                #pragma unroll
                for (int j = 0; j < FN; ++j)
                    acc[i][j] = mfma16(af[i], bfr[j], acc[i][j]);
        }
        __syncthreads();
    }
    #pragma unroll
    for (int i = 0; i < FM; ++i) {
        int rbase = m0 + wm + i * 16 + lg * 4;
        #pragma unroll
        for (int j = 0; j < FN; ++j) {
            int col = n0 + wn + j * 16 + lc;
            if (col >= N) continue;
            float bn = biasN ? (float)biasN[col] : 0.0f;
            #pragma unroll
            for (int r = 0; r < 4; ++r) {
                int row = rbase + r;
                if (row < M) {
                    float v = acc[i][j][r] + bn;
                    if (biasM) v += (float)biasM[row];
                    C[(size_t)row * ldc + col] = __float2bfloat16(v * csc);
                }
            }
        }
    }
}

// ---------------- merged qkv projection GEMM (zero-waste job shapes)
__global__ __launch_bounds__(256, 2) void qkv_gemm(
    const __hip_bfloat16* __restrict__ Xc,
    const __hip_bfloat16* __restrict__ WqkT,
    const __hip_bfloat16* __restrict__ WvT,
    __hip_bfloat16* __restrict__ qk,
    __hip_bfloat16* __restrict__ vTo,
    const __hip_bfloat16* __restrict__ bqk,
    const __hip_bfloat16* __restrict__ bv,
    float qscale)
{
    __shared__ __align__(16) __hip_bfloat16 smem[192 * 64];
    const int bid = blockIdx.x;
    if (bid < 1024) {
        int z1 = bid >> 6, yt = bid & 63;
        gemm_body<128, 64>(
            Xc, WqkT + z1 * 32768, qk + (size_t)z1 * 524288,
            8192, 64, yt * 128, 0, 64,
            nullptr, bqk + z1 * 64, (z1 < 8) ? qscale : 1.0f,
            smem, smem + 128 * 64);
    } else {
        int t = bid - 1024, z = t >> 4, xt = t & 15;
        int h = z >> 2, b = z & 3;
        gemm_body<64, 128>(
            WvT + h * 32768, Xc + (size_t)b * 1048576,
            vTo + (size_t)h * 524288 + b * 131072,
            64, 2048, 0, xt * 128, 2048,
            bv + h * 64, nullptr, 1.0f,
            smem, smem + 64 * 64);
    }
}

// ---------------- generic MFMA GEMM (up/out), XOR-swizzled LDS
template<int BM, int BN>
__global__ __launch_bounds__(256, 2) void gemm_bt(
    const __hip_bfloat16* __restrict__ A,
    const __hip_bfloat16* __restrict__ B,
    void* __restrict__ C,
    int M, int N, int K, int lda, int ldb, int ldc,
    long sA1, long sA0, long sB1, long sB0, long sC1, long sC0,
    const __hip_bfloat16* __restrict__ biasM, long sbM1,
    const __hip_bfloat16* __restrict__ biasN, long sbN1,
    int Z0, const int* __restrict__ outF32flag, float cscale, int scaleZmax)
{
    constexpr int BK = 64;
    const int z = blockIdx.z;
    const int z1 = z / Z0, z0 = z - z1 * Z0;
    A += (size_t)z1 * sA1 + (size_t)z0 * sA0;
    B += (size_t)z1 * sB1 + (size_t)z0 * sB0;
    const size_t cbase = (size_t)z1 * sC1 + (size_t)z0 * sC0;
    if (biasM) biasM += (size_t)z1 * sbM1;
    if (biasN) biasN += (size_t)z1 * sbN1;
    const int outF32 = outF32flag ? *outF32flag : 0;
    const float csc = (z1 < scaleZmax) ? cscale : 1.0f;

    __shared__ __align__(16) __hip_bfloat16 lA[BM * BK];
    __shared__ __align__(16) __hip_bfloat16 lB[BN * BK];
    const int tid = threadIdx.x, lane = tid & 63, wave = tid >> 6;
    const int m0 = blockIdx.y * BM, n0 = blockIdx.x * BN;
    constexpr int WM = BM / 2, WN = BN / 2, FM = WM / 16, FN = WN / 16;
    const int wm = (wave >> 1) * WM, wn = (wave & 1) * WN;
    const int lc = lane & 15, lg = lane >> 4;

    f32x4 acc[FM][FN] = {};
    constexpr int CA = BM * 8 / 256, CB = BN * 8 / 256;

    for (int k0 = 0; k0 < K; k0 += BK) {
        #pragma unroll
        for (int j = 0; j < CA; ++j) {
            int ch = j * 256 + tid;
            int m = ch >> 3, kc = (ch & 7) ^ (m & 7);
            int mg = m0 + m; if (mg > M - 1) mg = M - 1;
            async16(&A[(size_t)mg * lda + k0 + kc * 8], &lA[ch * 8]);
        }
        #pragma unroll
        for (int j = 0; j < CB; ++j) {
            int ch = j * 256 + tid;
            int n = ch >> 3, kc = (ch & 7) ^ (n & 7);
            int ng = n0 + n; if (ng > N - 1) ng = N - 1;
            async16(&B[(size_t)ng * ldb + k0 + kc * 8], &lB[ch * 8]);
        }
        __syncthreads();
        #pragma unroll
        for (int ks = 0; ks < BK; ks += 32) {
            bf16x8 af[FM], bfr[FN];
            #pragma unroll
            for (int i = 0; i < FM; ++i) {
                int row = wm + i * 16 + lc;
                af[i] = *(const bf16x8*)&lA[row * 64 + (((ks >> 3) + lg) ^ (row & 7)) * 8];
            }
            #pragma unroll
            for (int j = 0; j < FN; ++j) {
                int row = wn + j * 16 + lc;
                bfr[j] = *(const bf16x8*)&lB[row * 64 + (((ks >> 3) + lg) ^ (row & 7)) * 8];
            }
            #pragma unroll
            for (int i = 0; i < FM; ++i)
                #pragma unroll
                for (int j = 0; j < FN; ++j)
                    acc[i][j] = mfma16(af[i], bfr[j], acc[i][j]);
        }
        __syncthreads();
    }
    #pragma unroll
    for (int i = 0; i < FM; ++i) {
        int rbase = m0 + wm + i * 16 + lg * 4;
        #pragma unroll
        for (int j = 0; j < FN; ++j) {
            int col = n0 + wn + j * 16 + lc;
            if (col >= N) continue;
            float bn = biasN ? (float)biasN[col] : 0.0f;
            #pragma unroll
            for (int r = 0; r < 4; ++r) {
                int row = rbase + r;
                if (row < M) {
                    float v = acc[i][j][r] + bn;
                    if (biasM) v += (float)biasM[row];
                    v *= csc;
                    size_t idx = cbase + (size_t)row * ldc + col;
                    if (outF32) ((float*)C)[idx] = v;
                    else ((__hip_bfloat16*)C)[idx] = __float2bfloat16(v);
                }
            }
        }
    }
}

// ---------------- flash attention v12: 512-thread blocks, 8 waves =
// 4 q-subtiles (32 rows each) x 2 t-parity groups. Group g processes tiles
// t = g, g+2, ..., g+30 using its own LDS double-buffer pair (64KB total).
// No running max (scores bounded, qscale=log2e/64 in q) -> t-split exact;
// partials combined through LDS at the end. waves_per_eu pinned 4..4 so the
// allocator uses the full 128-VGPR budget instead of spilling to hit an
// occupancy tier the LDS cap makes unreachable (see header).
// q,k: [H*B][S][64]; vT: [H*B][64][S]; out cT: [B][512][S]
__global__ __launch_bounds__(512)
__attribute__((amdgpu_waves_per_eu(4, 4))) void flash_attn(
    const __hip_bfloat16* __restrict__ q,
    const __hip_bfloat16* __restrict__ k,
    const __hip_bfloat16* __restrict__ vT,
    __hip_bfloat16* __restrict__ cT)
{
    const int S = 2048;
    const int h = blockIdx.y >> 2, b = blockIdx.y & 3;
    const int tid = threadIdx.x, lane = tid & 63;
    const int qw = (tid >> 6) & 3;     // q sub-tile (32 rows) within block
    const int grp = tid >> 8;          // t-parity group: 0 = even tiles, 1 = odd
    const int lc = lane & 15, lg = lane >> 4;
    const int s0 = blockIdx.x * 128 + qw * 32;

    const __hip_bfloat16* qb = q  + (size_t)(h * 4 + b) * S * 64;
    const __hip_bfloat16* kb = k  + (size_t)(h * 4 + b) * S * 64;
    const __hip_bfloat16* vb = vT + (size_t)(h * 4 + b) * 64 * S;

    // 64KB: buffer b in [b*8192, b*8192+8191]: K tile 4096 elems, V tile 4096.
    // group g owns buffers {g, g+2} -> bases g*8192 + {0, 16384}.
    __shared__ __align__(16) __hip_bfloat16 smem[32768];
    const int gbase = grp * 8192;

    bf16x8 qf[2][2];
    #pragma unroll
    for (int f = 0; f < 2; ++f)
        #pragma unroll
        for (int hh = 0; hh < 2; ++hh)
            qf[f][hh] = *(const bf16x8*)&qb[(size_t)(s0 + f * 16 + lc) * 64 + hh * 32 + lg * 8];

    // lane-constant offset BASES (elements); kg/dt walk via literal offsets.
    // swizzle sw = (row&7) = (lc&7) for every row=...*16+lc (16 == 0 mod 8).
    // K group index for hh=1 is (lg+4)^sw = (lg^sw)^4 -> koff1 = koff0 ^ 32.
    const int sw = lc & 7;
    const int koff0 = gbase + lc * 64 + ((lg ^ sw)) * 8;             // +kg*1024
    const int koff1 = koff0 ^ 32;                                    // +kg*1024
    int voffk[4];
    #pragma unroll
    for (int kg = 0; kg < 4; ++kg)
        voffk[kg] = gbase + 4096 + lc * 64 +
                    ((2 * kg + (lg >> 1)) ^ sw) * 8 + (lg & 1) * 4;  // +dt*1024

    // staging offsets: each group (256 threads) stages its own 16KB tile;
    // 2 K-chunks + 2 V-chunks per thread, XOR-swizzled like the GEMMs.
    // chunk ch+256: row+32 == row (mod 8) -> same swizzle -> j=1 offsets are
    // j=0 + {2048 lds, 2048 K-elems, 32*S V-elems}.
    const int tidg = tid & 255;
    const int srow = tidg >> 3, scg = (tidg & 7) ^ (srow & 7);
    const int sld = gbase + tidg * 8;            // LDS K dest; V dest +4096
    const int kgo = srow * 64 + scg * 8;
    const size_t vgo = (size_t)srow * S + scg * 8;

    // prologue: group g stages its first tile (t = g) into its cur=0 buffer
    {
        const size_t kt = (size_t)grp * 4096, vt = (size_t)grp * 64;
        async16(&kb[kt + kgo],        &smem[sld]);
        async16(&kb[kt + kgo + 2048], &smem[sld + 2048]);
        async16(&vb[vgo + vt],         &smem[sld + 4096]);
        async16(&vb[vgo + vt + 65536], &smem[sld + 6144]);
    }
    __syncthreads();

    f32x4 O[2][4] = {};
    float lsum[2] = {0.0f, 0.0f};

    auto step = [&](int i, int cur) {
        if (i < 15) {  // prefetch this group's tile t+2 into the other buffer
            const int tn = grp + 2 * i + 2;
            const int nxt = cur ^ 16384;
            const size_t kt = (size_t)tn * 4096, vt = (size_t)tn * 64;
            async16(&kb[kt + kgo],        &smem[sld + nxt]);
            async16(&kb[kt + kgo + 2048], &smem[sld + nxt + 2048]);
            async16(&vb[vgo + vt],         &smem[sld + nxt + 4096]);
            async16(&vb[vgo + vt + 65536], &smem[sld + nxt + 6144]);
        }
        __builtin_amdgcn_s_setprio(1);
        #pragma unroll
        for (int kg = 0; kg < 4; ++kg) {
            bf16x8 kf0 = *(const bf16x8*)&smem[cur + koff0 + kg * 1024];
            bf16x8 kf1 = *(const bf16x8*)&smem[cur + koff1 + kg * 1024];
            short4v pb0, pb1;
            {
                f32x4 s = {};
                s = mfma16(kf0, qf[0][0], s);
                s = mfma16(kf1, qf[0][1], s);
                f32x4 e;
                #pragma unroll
                for (int r = 0; r < 4; ++r) e[r] = fexp2(s[r]);
                lsum[0] += (e[0] + e[1]) + (e[2] + e[3]);
                pb0 = pack_bf16x4(e);
            }
            {
                f32x4 s = {};
                s = mfma16(kf0, qf[1][0], s);
                s = mfma16(kf1, qf[1][1], s);
                f32x4 e;
                #pragma unroll
                for (int r = 0; r < 4; ++r) e[r] = fexp2(s[r]);
                lsum[1] += (e[0] + e[1]) + (e[2] + e[3]);
                pb1 = pack_bf16x4(e);
            }
            #pragma unroll
            for (int dt = 0; dt < 4; ++dt) {
                short4v vf = *(const short4v*)&smem[cur + voffk[kg] + dt * 1024];
                O[0][dt] = mfma16k(vf, pb0, O[0][dt]);
                O[1][dt] = mfma16k(vf, pb1, O[1][dt]);
            }
        }
        __builtin_amdgcn_s_setprio(0);
        __syncthreads();
    };

    for (int i = 0; i < 16; i += 2) {
        step(i, 0);
        step(i + 1, 16384);
    }

    // ---- combine the two t-halves through LDS (buffers dead after last barrier)
    // grp1 partials: O at f32[0..8191] (32KB), lsum at f32[8192..8703] (2KB)
    float* pf = (float*)smem;
    if (grp == 1) {
        #pragma unroll
        for (int f = 0; f < 2; ++f) {
            #pragma unroll
            for (int dt = 0; dt < 4; ++dt) {
                int base = (((qw * 2 + f) * 4 + dt) * 4) * 64 + lane;
                #pragma unroll
                for (int r = 0; r < 4; ++r) pf[base + r * 64] = O[f][dt][r];
            }
            pf[8192 + (qw * 2 + f) * 64 + lane] = lsum[f];
        }
    }
    __syncthreads();
    __hip_bfloat16* tb = &smem[20480];   // transpose buffer [64][136], disjoint from pf
    if (grp == 0) {
        float inv[2];
        #pragma unroll
        for (int f = 0; f < 2; ++f) {
            #pragma unroll
            for (int dt = 0; dt < 4; ++dt) {
                int base = (((qw * 2 + f) * 4 + dt) * 4) * 64 + lane;
                #pragma unroll
                for (int r = 0; r < 4; ++r) O[f][dt][r] += pf[base + r * 64];
            }
            float v = lsum[f] + pf[8192 + (qw * 2 + f) * 64 + lane];
            v += __shfl_xor(v, 16);
            v += __shfl_xor(v, 32);
            inv[f] = 1.0f / v;
        }
        #pragma unroll
        for (int f = 0; f < 2; ++f)
            #pragma unroll
            for (int dt = 0; dt < 4; ++dt)
                #pragma unroll
                for (int r = 0; r < 4; ++r)
                    tb[(dt * 16 + lg * 4 + r) * 136 + qw * 32 + f * 16 + lc] =
                        __float2bfloat16(O[f][dt][r] * inv[f]);
    }
    __syncthreads();
    int row = tid >> 3, c0 = (tid & 7) * 16;
    size_t off = ((size_t)b * 512 + h * 64 + row) * S + blockIdx.x * 128 + c0;
    #pragma unroll
    for (int cc = 0; cc < 2; ++cc)
        *(bf16x8*)&cT[off + cc * 8] = *(const bf16x8*)&tb[row * 136 + c0 + cc * 8];
}

extern "C" void kernel_launch(void* const* d_in, const int* in_sizes, int n_in,
                              void* d_out, int out_size, void* d_ws, size_t ws_size,
                              hipStream_t stream) {
    using bf = __hip_bfloat16;
    bf* ws = (bf*)d_ws;
    int* flag = (int*)d_ws;
    bf* bqc = ws + 64;
    bf* bkc = ws + 576;
    bf* bvc = ws + 1088;
    bf* btc = ws + 1600;
    bf* boc = ws + 2320;
    bf* WqT = ws + 4096;       // [8][64][512]; WkT contiguous after
    bf* WkT = ws + 266240;
    bf* WvT = ws + 528384;
    bf* Wtc = ws + 790528;     // [720][2048]
    bf* Woc = ws + 2265088;    // [512][512]
    bf* Xc  = ws + 2527232;    // [4][2048][512], dead after qkv gemm
    bf* cT  = ws + 2527232;    // [4][512][2048], overlays Xc
    bf* q   = ws + 6721536;    // [32][2048][64]; kk contiguous after
    bf* up  = ws + 6721536;    // [4][720][512], overlays q after flash
    bf* kk  = ws + 10915840;   // [32][2048][64]
    bf* vT  = ws + 15110144;   // [32][64][2048]

    CTab tab;
    tab.t[0]  = { d_in[0],  Xc,  4194304, 0 };
    tab.t[1]  = { d_in[1],  WqT, 262144,  1 };
    tab.t[2]  = { d_in[2],  bqc, 512,     0 };
    tab.t[3]  = { d_in[3],  WkT, 262144,  1 };
    tab.t[4]  = { d_in[4],  bkc, 512,     0 };
    tab.t[5]  = { d_in[5],  WvT, 262144,  1 };
    tab.t[6]  = { d_in[6],  bvc, 512,     0 };
    tab.t[7]  = { d_in[7],  Wtc, 1474560, 0 };
    tab.t[8]  = { d_in[8],  btc, 720,     0 };
    tab.t[9]  = { d_in[9],  Woc, 262144,  0 };
    tab.t[10] = { d_in[10], boc, 512,     0 };
    convert_all<<<dim3(2048, 11), 256, 0, stream>>>(tab, (const unsigned*)d_in[0], flag);

    const float qscale = 0.022542110013890054f;  // log2(e)/64
    qkv_gemm<<<dim3(1536), 256, 0, stream>>>(Xc, WqT, WvT, q, vT, bqc, bvc, qscale);

    flash_attn<<<dim3(16, 32), 512, 0, stream>>>(q, kk, vT, cT);

    // up[b] = Wt * cT[b]^T + bt (per-row)  (z1=b); 384 blocks
    gemm_bt<64, 64><<<dim3(8, 12, 4), 256, 0, stream>>>(
        Wtc, cT, up, 720, 512, 2048, 2048, 2048, 512,
        0, 0, 1048576, 0, 368640, 0, btc, 0, nullptr, 0, 1, nullptr, 1.0f, 0);

    // out = up * Woc^T + bo (per-col); dtype per probed flag; 360 blocks
    gemm_bt<64, 64><<<dim3(8, 45, 1), 256, 0, stream>>>(
        up, Woc, d_out, 2880, 512, 512, 512, 512, 512,
        0, 0, 0, 0, 0, 0, nullptr, 0, boc, 0, 1, flag, 1.0f, 0);
}

// Round 5
// 195.853 us; speedup vs baseline: 1.0279x; 1.0279x over previous
//
#include <hip/hip_runtime.h>
#include <hip/hip_bf16.h>

// Model_3315714753203: B=4,S=2048,I=512,D=512,H=8,HD=64,P=720.
// fp32 inputs (probed in convert) -> internal bf16.
// 5 dispatches: convert(+inline probe) -> qkv2 (128x128 tiles) -> flash v11 ->
// GEMM up -> GEMM out. ALL GEMM LDS tiles XOR-chunk-swizzled.
// r4: qkv rebuilt as 768-block 128x128-tile kernel (2x MFMA density vs the
// old 128x64/64x128 job tiles): q|k = one M=8192 N=1024 GEMM (Wq|Wk and
// bq|bk are contiguous in ws) with head-scatter epilogue; v = M=512(h,d)
// N=2048(s) per batch with transpose-scatter epilogue. convert grid trimmed
// 2048->512 blocks.x. flash = v11 exact (v12's waves_per_eu attr was a no-op:
// identical VGPR/WRITE/dur; ~8MB one-time spill costs only ~3us).

typedef short bf16x8 __attribute__((ext_vector_type(8)));
typedef short short4v __attribute__((ext_vector_type(4)));
typedef float f32x4 __attribute__((ext_vector_type(4)));
typedef const __attribute__((address_space(1))) void* gptr_t;
typedef __attribute__((address_space(3))) void* sptr_t;

__device__ __forceinline__ f32x4 mfma16(bf16x8 a, bf16x8 b, f32x4 c) {
    return __builtin_amdgcn_mfma_f32_16x16x32_bf16(a, b, c, 0, 0, 0);
}
__device__ __forceinline__ f32x4 mfma16k(short4v a, short4v b, f32x4 c) {
#if __has_builtin(__builtin_amdgcn_mfma_f32_16x16x16bf16_1k)
    return __builtin_amdgcn_mfma_f32_16x16x16bf16_1k(a, b, c, 0, 0, 0);
#else
    (void)a; (void)b; return c;   // host-pass stub
#endif
}
__device__ __forceinline__ void async16(const void* g, void* l) {
    __builtin_amdgcn_global_load_lds((gptr_t)g, (sptr_t)l, 16, 0, 0);
}
// raw v_exp_f32 (OCML exp2f adds ~6 insts of fixup we don't need: scores bounded)
__device__ __forceinline__ float fexp2(float x) {
#if __has_builtin(__builtin_amdgcn_exp2f)
    return __builtin_amdgcn_exp2f(x);
#else
    return exp2f(x);
#endif
}
// pack 4 f32 -> 4 bf16 (round-half-up: +0x8000, take high 16)
__device__ __forceinline__ short4v pack_bf16x4(f32x4 v) {
    unsigned a = __builtin_bit_cast(unsigned, v[0]) + 0x8000u;
    unsigned b = __builtin_bit_cast(unsigned, v[1]) + 0x8000u;
    unsigned c = __builtin_bit_cast(unsigned, v[2]) + 0x8000u;
    unsigned d = __builtin_bit_cast(unsigned, v[3]) + 0x8000u;
    int2 t;
    t.x = (int)__builtin_amdgcn_perm(b, a, 0x07060302u);
    t.y = (int)__builtin_amdgcn_perm(d, c, 0x07060302u);
    return __builtin_bit_cast(short4v, t);
}

// ---------------- convert all inputs to bf16, inline dtype probe
struct CDesc { const void* s; __hip_bfloat16* d; int n; int mode; };
struct CTab  { CDesc t[11]; };

__global__ void convert_all(CTab tab, const unsigned* __restrict__ x0,
                            int* __restrict__ flag) {
    __shared__ int sflag;
    if (threadIdx.x < 64) {
        unsigned e = (x0[threadIdx.x] >> 23) & 0xffu;
        unsigned long long m = __ballot(e >= 100u && e <= 145u);
        if (threadIdx.x == 0) sflag = (__popcll(m) >= 32) ? 1 : 0;
    }
    __syncthreads();
    const int isF32 = sflag;
    if (blockIdx.x == 0 && blockIdx.y == 0 && threadIdx.x == 0) *flag = isF32;

    CDesc de = tab.t[blockIdx.y];
    for (int i = blockIdx.x * 256 + threadIdx.x; i < de.n; i += gridDim.x * 256) {
        int si = i;
        if (de.mode) {  // dst [h][d][i512] <- src [h][i512][d]
            int ii = i & 511, d = (i >> 9) & 63, h = i >> 15;
            si = (h * 512 + ii) * 64 + d;
        }
        float v = isF32 ? ((const float*)de.s)[si]
                        : (float)((const __hip_bfloat16*)de.s)[si];
        de.d[i] = __float2bfloat16(v);
    }
}

// ---------------- generic GEMM core (K=512), XOR-swizzled LDS tiles,
// epilogue via functor (val, row, col). BM=BN=128: FM=FN=4, 16 MFMA/ks.
template<int BM, int BN, class EPI>
__device__ __forceinline__ void gemm_core(
    const __hip_bfloat16* __restrict__ A,
    const __hip_bfloat16* __restrict__ B,
    int lda, int ldb, int M, int N, int m0, int n0,
    __hip_bfloat16* lA, __hip_bfloat16* lB, EPI epi)
{
    constexpr int FM = BM / 32, FN = BN / 32;
    const int tid = threadIdx.x, lane = tid & 63, wave = tid >> 6;
    const int wm = (wave >> 1) * (BM / 2), wn = (wave & 1) * (BN / 2);
    const int lc = lane & 15, lg = lane >> 4;

    f32x4 acc[FM][FN] = {};
    constexpr int CA = BM * 8 / 256, CB = BN * 8 / 256;

    for (int k0 = 0; k0 < 512; k0 += 64) {
        #pragma unroll
        for (int j = 0; j < CA; ++j) {
            int ch = j * 256 + tid;
            int m = ch >> 3, kc = (ch & 7) ^ (m & 7);
            int mg = m0 + m; if (mg > M - 1) mg = M - 1;
            async16(&A[(size_t)mg * lda + k0 + kc * 8], &lA[ch * 8]);
        }
        #pragma unroll
        for (int j = 0; j < CB; ++j) {
            int ch = j * 256 + tid;
            int n = ch >> 3, kc = (ch & 7) ^ (n & 7);
            int ng = n0 + n; if (ng > N - 1) ng = N - 1;
            async16(&B[(size_t)ng * ldb + k0 + kc * 8], &lB[ch * 8]);
        }
        __syncthreads();
        #pragma unroll
        for (int ks = 0; ks < 64; ks += 32) {
            bf16x8 af[FM], bfr[FN];
            #pragma unroll
            for (int i = 0; i < FM; ++i) {
                int row = wm + i * 16 + lc;
                af[i] = *(const bf16x8*)&lA[row * 64 + (((ks >> 3) + lg) ^ (row & 7)) * 8];
            }
            #pragma unroll
            for (int j = 0; j < FN; ++j) {
                int row = wn + j * 16 + lc;
                bfr[j] = *(const bf16x8*)&lB[row * 64 + (((ks >> 3) + lg) ^ (row & 7)) * 8];
            }
            #pragma unroll
            for (int i = 0; i < FM; ++i)
                #pragma unroll
                for (int j = 0; j < FN; ++j)
                    acc[i][j] = mfma16(af[i], bfr[j], acc[i][j]);
        }
        __syncthreads();
    }
    #pragma unroll
    for (int i = 0; i < FM; ++i) {
        int rbase = m0 + wm + i * 16 + lg * 4;
        #pragma unroll
        for (int j = 0; j < FN; ++j) {
            int col = n0 + wn + j * 16 + lc;
            #pragma unroll
            for (int r = 0; r < 4; ++r)
                epi(acc[i][j][r], rbase + r, col);
        }
    }
}

// ---------------- qkv2: 128x128-tile merged projections.
// bid<512: q|k GEMM M=8192(b,s) N=1024(head-d; 0..511=q, 512..1023=k) K=512.
//   Wqk rows (h*64+d) contiguous (WqT then WkT in ws); bqk likewise.
//   Epilogue scatters to q/kk [h*4+b][s][64] and scales q cols by qscale.
// bid>=512: v GEMM M=512(h,d) N=2048(s) K=512, per batch b.
//   Epilogue scatters to vT [h*4+b][64][2048] (+bv per row).
__global__ __launch_bounds__(256, 2) void qkv_gemm(
    const __hip_bfloat16* __restrict__ Xc,
    const __hip_bfloat16* __restrict__ WqkT,
    const __hip_bfloat16* __restrict__ WvT,
    __hip_bfloat16* __restrict__ qk,
    __hip_bfloat16* __restrict__ vTo,
    const __hip_bfloat16* __restrict__ bqk,
    const __hip_bfloat16* __restrict__ bv,
    float qscale)
{
    __shared__ __align__(16) __hip_bfloat16 smem[2 * 128 * 64];
    const int bid = blockIdx.x;
    if (bid < 512) {
        const int m0 = (bid & 63) * 128, n0 = (bid >> 6) * 128;
        gemm_core<128, 128>(
            Xc, WqkT, 512, 512, 8192, 1024, m0, n0,
            smem, smem + 128 * 64,
            [&](float v, int row, int col) {
                v += (float)bqk[col];
                if (col < 512) v *= qscale;
                int hd = col & 511, hh = hd >> 6, d = hd & 63;
                int bb = row >> 11, s = row & 2047;
                size_t off = (size_t)(col >> 9) * 4194304 +
                             (size_t)(hh * 4 + bb) * 131072 + s * 64 + d;
                qk[off] = __float2bfloat16(v);
            });
    } else {
        const int t = bid - 512;
        const int bb = t >> 6, r = t & 63;
        const int m0 = (r >> 4) * 128, n0 = (r & 15) * 128;
        gemm_core<128, 128>(
            WvT, Xc + (size_t)bb * 1048576, 512, 512, 512, 2048, m0, n0,
            smem, smem + 128 * 64,
            [&](float v, int row, int col) {
                v += (float)bv[row];
                int hh = row >> 6, d = row & 63;
                size_t off = (size_t)hh * 524288 + (size_t)bb * 131072 +
                             d * 2048 + col;
                vTo[off] = __float2bfloat16(v);
            });
    }
}

// ---------------- generic MFMA GEMM (up/out), XOR-swizzled LDS
template<int BM, int BN>
__global__ __launch_bounds__(256, 2) void gemm_bt(
    const __hip_bfloat16* __restrict__ A,
    const __hip_bfloat16* __restrict__ B,
    void* __restrict__ C,
    int M, int N, int K, int lda, int ldb, int ldc,
    long sA1, long sA0, long sB1, long sB0, long sC1, long sC0,
    const __hip_bfloat16* __restrict__ biasM, long sbM1,
    const __hip_bfloat16* __restrict__ biasN, long sbN1,
    int Z0, const int* __restrict__ outF32flag, float cscale, int scaleZmax)
{
    constexpr int BK = 64;
    const int z = blockIdx.z;
    const int z1 = z / Z0, z0 = z - z1 * Z0;
    A += (size_t)z1 * sA1 + (size_t)z0 * sA0;
    B += (size_t)z1 * sB1 + (size_t)z0 * sB0;
    const size_t cbase = (size_t)z1 * sC1 + (size_t)z0 * sC0;
    if (biasM) biasM += (size_t)z1 * sbM1;
    if (biasN) biasN += (size_t)z1 * sbN1;
    const int outF32 = outF32flag ? *outF32flag : 0;
    const float csc = (z1 < scaleZmax) ? cscale : 1.0f;

    __shared__ __align__(16) __hip_bfloat16 lA[BM * BK];
    __shared__ __align__(16) __hip_bfloat16 lB[BN * BK];
    const int tid = threadIdx.x, lane = tid & 63, wave = tid >> 6;
    const int m0 = blockIdx.y * BM, n0 = blockIdx.x * BN;
    constexpr int WM = BM / 2, WN = BN / 2, FM = WM / 16, FN = WN / 16;
    const int wm = (wave >> 1) * WM, wn = (wave & 1) * WN;
    const int lc = lane & 15, lg = lane >> 4;

    f32x4 acc[FM][FN] = {};
    constexpr int CA = BM * 8 / 256, CB = BN * 8 / 256;

    for (int k0 = 0; k0 < K; k0 += BK) {
        #pragma unroll
        for (int j = 0; j < CA; ++j) {
            int ch = j * 256 + tid;
            int m = ch >> 3, kc = (ch & 7) ^ (m & 7);
            int mg = m0 + m; if (mg > M - 1) mg = M - 1;
            async16(&A[(size_t)mg * lda + k0 + kc * 8], &lA[ch * 8]);
        }
        #pragma unroll
        for (int j = 0; j < CB; ++j) {
            int ch = j * 256 + tid;
            int n = ch >> 3, kc = (ch & 7) ^ (n & 7);
            int ng = n0 + n; if (ng > N - 1) ng = N - 1;
            async16(&B[(size_t)ng * ldb + k0 + kc * 8], &lB[ch * 8]);
        }
        __syncthreads();
        #pragma unroll
        for (int ks = 0; ks < BK; ks += 32) {
            bf16x8 af[FM], bfr[FN];
            #pragma unroll
            for (int i = 0; i < FM; ++i) {
                int row = wm + i * 16 + lc;
                af[i] = *(const bf16x8*)&lA[row * 64 + (((ks >> 3) + lg) ^ (row & 7)) * 8];
            }
            #pragma unroll
            for (int j = 0; j < FN; ++j) {
                int row = wn + j * 16 + lc;
                bfr[j] = *(const bf16x8*)&lB[row * 64 + (((ks >> 3) + lg) ^ (row & 7)) * 8];
            }
            #pragma unroll
            for (int i = 0; i < FM; ++i)
                #pragma unroll
                for (int j = 0; j < FN; ++j)
                    acc[i][j] = mfma16(af[i], bfr[j], acc[i][j]);
        }
        __syncthreads();
    }
    #pragma unroll
    for (int i = 0; i < FM; ++i) {
        int rbase = m0 + wm + i * 16 + lg * 4;
        #pragma unroll
        for (int j = 0; j < FN; ++j) {
            int col = n0 + wn + j * 16 + lc;
            if (col >= N) continue;
            float bn = biasN ? (float)biasN[col] : 0.0f;
            #pragma unroll
            for (int r = 0; r < 4; ++r) {
                int row = rbase + r;
                if (row < M) {
                    float v = acc[i][j][r] + bn;
                    if (biasM) v += (float)biasM[row];
                    v *= csc;
                    size_t idx = cbase + (size_t)row * ldc + col;
                    if (outF32) ((float*)C)[idx] = v;
                    else ((__hip_bfloat16*)C)[idx] = __float2bfloat16(v);
                }
            }
        }
    }
}

// ---------------- flash attention v11: 512-thread blocks, 8 waves =
// 4 q-subtiles (32 rows each) x 2 t-parity groups. Group g processes tiles
// t = g, g+2, ..., g+30 using its own LDS double-buffer pair (64KB total).
// No running max (scores bounded, qscale=log2e/64 in q) -> t-split exact;
// partials combined through LDS at the end.
// q,k: [H*B][S][64]; vT: [H*B][64][S]; out cT: [B][512][S]
__global__ __launch_bounds__(512, 4) void flash_attn(
    const __hip_bfloat16* __restrict__ q,
    const __hip_bfloat16* __restrict__ k,
    const __hip_bfloat16* __restrict__ vT,
    __hip_bfloat16* __restrict__ cT)
{
    const int S = 2048;
    const int h = blockIdx.y >> 2, b = blockIdx.y & 3;
    const int tid = threadIdx.x, lane = tid & 63;
    const int qw = (tid >> 6) & 3;     // q sub-tile (32 rows) within block
    const int grp = tid >> 8;          // t-parity group: 0 = even tiles, 1 = odd
    const int lc = lane & 15, lg = lane >> 4;
    const int s0 = blockIdx.x * 128 + qw * 32;

    const __hip_bfloat16* qb = q  + (size_t)(h * 4 + b) * S * 64;
    const __hip_bfloat16* kb = k  + (size_t)(h * 4 + b) * S * 64;
    const __hip_bfloat16* vb = vT + (size_t)(h * 4 + b) * 64 * S;

    // 64KB: buffer b in [b*8192, b*8192+8191]: K tile 4096 elems, V tile 4096.
    // group g owns buffers {g, g+2} -> bases g*8192 + {0, 16384}.
    __shared__ __align__(16) __hip_bfloat16 smem[32768];
    const int gbase = grp * 8192;

    bf16x8 qf[2][2];
    #pragma unroll
    for (int f = 0; f < 2; ++f)
        #pragma unroll
        for (int hh = 0; hh < 2; ++hh)
            qf[f][hh] = *(const bf16x8*)&qb[(size_t)(s0 + f * 16 + lc) * 64 + hh * 32 + lg * 8];

    // lane-constant offset BASES (elements); kg/dt walk via literal offsets.
    // swizzle sw = (row&7) = (lc&7) for every row=...*16+lc (16 == 0 mod 8).
    // K group index for hh=1 is (lg+4)^sw = (lg^sw)^4 -> koff1 = koff0 ^ 32.
    const int sw = lc & 7;
    const int koff0 = gbase + lc * 64 + ((lg ^ sw)) * 8;             // +kg*1024
    const int koff1 = koff0 ^ 32;                                    // +kg*1024
    int voffk[4];
    #pragma unroll
    for (int kg = 0; kg < 4; ++kg)
        voffk[kg] = gbase + 4096 + lc * 64 +
                    ((2 * kg + (lg >> 1)) ^ sw) * 8 + (lg & 1) * 4;  // +dt*1024

    // staging offsets: each group (256 threads) stages its own 16KB tile;
    // 2 K-chunks + 2 V-chunks per thread, XOR-swizzled like the GEMMs.
    // chunk ch+256: row+32 == row (mod 8) -> same swizzle -> j=1 offsets are
    // j=0 + {2048 lds, 2048 K-elems, 32*S V-elems}.
    const int tidg = tid & 255;
    const int srow = tidg >> 3, scg = (tidg & 7) ^ (srow & 7);
    const int sld = gbase + tidg * 8;            // LDS K dest; V dest +4096
    const int kgo = srow * 64 + scg * 8;
    const size_t vgo = (size_t)srow * S + scg * 8;

    // prologue: group g stages its first tile (t = g) into its cur=0 buffer
    {
        const size_t kt = (size_t)grp * 4096, vt = (size_t)grp * 64;
        async16(&kb[kt + kgo],        &smem[sld]);
        async16(&kb[kt + kgo + 2048], &smem[sld + 2048]);
        async16(&vb[vgo + vt],         &smem[sld + 4096]);
        async16(&vb[vgo + vt + 65536], &smem[sld + 6144]);
    }
    __syncthreads();

    f32x4 O[2][4] = {};
    float lsum[2] = {0.0f, 0.0f};

    auto step = [&](int i, int cur) {
        if (i < 15) {  // prefetch this group's tile t+2 into the other buffer
            const int tn = grp + 2 * i + 2;
            const int nxt = cur ^ 16384;
            const size_t kt = (size_t)tn * 4096, vt = (size_t)tn * 64;
            async16(&kb[kt + kgo],        &smem[sld + nxt]);
            async16(&kb[kt + kgo + 2048], &smem[sld + nxt + 2048]);
            async16(&vb[vgo + vt],         &smem[sld + nxt + 4096]);
            async16(&vb[vgo + vt + 65536], &smem[sld + nxt + 6144]);
        }
        __builtin_amdgcn_s_setprio(1);
        #pragma unroll
        for (int kg = 0; kg < 4; ++kg) {
            bf16x8 kf0 = *(const bf16x8*)&smem[cur + koff0 + kg * 1024];
            bf16x8 kf1 = *(const bf16x8*)&smem[cur + koff1 + kg * 1024];
            short4v pb0, pb1;
            {
                f32x4 s = {};
                s = mfma16(kf0, qf[0][0], s);
                s = mfma16(kf1, qf[0][1], s);
                f32x4 e;
                #pragma unroll
                for (int r = 0; r < 4; ++r) e[r] = fexp2(s[r]);
                lsum[0] += (e[0] + e[1]) + (e[2] + e[3]);
                pb0 = pack_bf16x4(e);
            }
            {
                f32x4 s = {};
                s = mfma16(kf0, qf[1][0], s);
                s = mfma16(kf1, qf[1][1], s);
                f32x4 e;
                #pragma unroll
                for (int r = 0; r < 4; ++r) e[r] = fexp2(s[r]);
                lsum[1] += (e[0] + e[1]) + (e[2] + e[3]);
                pb1 = pack_bf16x4(e);
            }
            #pragma unroll
            for (int dt = 0; dt < 4; ++dt) {
                short4v vf = *(const short4v*)&smem[cur + voffk[kg] + dt * 1024];
                O[0][dt] = mfma16k(vf, pb0, O[0][dt]);
                O[1][dt] = mfma16k(vf, pb1, O[1][dt]);
            }
        }
        __builtin_amdgcn_s_setprio(0);
        __syncthreads();
    };

    for (int i = 0; i < 16; i += 2) {
        step(i, 0);
        step(i + 1, 16384);
    }

    // ---- combine the two t-halves through LDS (buffers dead after last barrier)
    // grp1 partials: O at f32[0..8191] (32KB), lsum at f32[8192..8703] (2KB)
    float* pf = (float*)smem;
    if (grp == 1) {
        #pragma unroll
        for (int f = 0; f < 2; ++f) {
            #pragma unroll
            for (int dt = 0; dt < 4; ++dt) {
                int base = (((qw * 2 + f) * 4 + dt) * 4) * 64 + lane;
                #pragma unroll
                for (int r = 0; r < 4; ++r) pf[base + r * 64] = O[f][dt][r];
            }
            pf[8192 + (qw * 2 + f) * 64 + lane] = lsum[f];
        }
    }
    __syncthreads();
    __hip_bfloat16* tb = &smem[20480];   // transpose buffer [64][136], disjoint from pf
    if (grp == 0) {
        float inv[2];
        #pragma unroll
        for (int f = 0; f < 2; ++f) {
            #pragma unroll
            for (int dt = 0; dt < 4; ++dt) {
                int base = (((qw * 2 + f) * 4 + dt) * 4) * 64 + lane;
                #pragma unroll
                for (int r = 0; r < 4; ++r) O[f][dt][r] += pf[base + r * 64];
            }
            float v = lsum[f] + pf[8192 + (qw * 2 + f) * 64 + lane];
            v += __shfl_xor(v, 16);
            v += __shfl_xor(v, 32);
            inv[f] = 1.0f / v;
        }
        #pragma unroll
        for (int f = 0; f < 2; ++f)
            #pragma unroll
            for (int dt = 0; dt < 4; ++dt)
                #pragma unroll
                for (int r = 0; r < 4; ++r)
                    tb[(dt * 16 + lg * 4 + r) * 136 + qw * 32 + f * 16 + lc] =
                        __float2bfloat16(O[f][dt][r] * inv[f]);
    }
    __syncthreads();
    int row = tid >> 3, c0 = (tid & 7) * 16;
    size_t off = ((size_t)b * 512 + h * 64 + row) * S + blockIdx.x * 128 + c0;
    #pragma unroll
    for (int cc = 0; cc < 2; ++cc)
        *(bf16x8*)&cT[off + cc * 8] = *(const bf16x8*)&tb[row * 136 + c0 + cc * 8];
}

extern "C" void kernel_launch(void* const* d_in, const int* in_sizes, int n_in,
                              void* d_out, int out_size, void* d_ws, size_t ws_size,
                              hipStream_t stream) {
    using bf = __hip_bfloat16;
    bf* ws = (bf*)d_ws;
    int* flag = (int*)d_ws;
    bf* bqc = ws + 64;         // bqc[512] then bkc[512] contiguous = bqk[1024]
    bf* bkc = ws + 576;
    bf* bvc = ws + 1088;
    bf* btc = ws + 1600;
    bf* boc = ws + 2320;
    bf* WqT = ws + 4096;       // [8][64][512]; WkT contiguous after = Wqk[1024][512]
    bf* WkT = ws + 266240;
    bf* WvT = ws + 528384;
    bf* Wtc = ws + 790528;     // [720][2048]
    bf* Woc = ws + 2265088;    // [512][512]
    bf* Xc  = ws + 2527232;    // [4][2048][512], dead after qkv gemm
    bf* cT  = ws + 2527232;    // [4][512][2048], overlays Xc
    bf* q   = ws + 6721536;    // [32][2048][64]; kk contiguous after (+4194304)
    bf* up  = ws + 6721536;    // [4][720][512], overlays q after flash
    bf* kk  = ws + 10915840;   // [32][2048][64]
    bf* vT  = ws + 15110144;   // [32][64][2048]

    CTab tab;
    tab.t[0]  = { d_in[0],  Xc,  4194304, 0 };
    tab.t[1]  = { d_in[1],  WqT, 262144,  1 };
    tab.t[2]  = { d_in[2],  bqc, 512,     0 };
    tab.t[3]  = { d_in[3],  WkT, 262144,  1 };
    tab.t[4]  = { d_in[4],  bkc, 512,     0 };
    tab.t[5]  = { d_in[5],  WvT, 262144,  1 };
    tab.t[6]  = { d_in[6],  bvc, 512,     0 };
    tab.t[7]  = { d_in[7],  Wtc, 1474560, 0 };
    tab.t[8]  = { d_in[8],  btc, 720,     0 };
    tab.t[9]  = { d_in[9],  Woc, 262144,  0 };
    tab.t[10] = { d_in[10], boc, 512,     0 };
    convert_all<<<dim3(512, 11), 256, 0, stream>>>(tab, (const unsigned*)d_in[0], flag);

    const float qscale = 0.022542110013890054f;  // log2(e)/64
    qkv_gemm<<<dim3(768), 256, 0, stream>>>(Xc, WqT, WvT, q, vT, bqc, bvc, qscale);

    flash_attn<<<dim3(16, 32), 512, 0, stream>>>(q, kk, vT, cT);

    // up[b] = Wt * cT[b]^T + bt (per-row)  (z1=b); 384 blocks
    gemm_bt<64, 64><<<dim3(8, 12, 4), 256, 0, stream>>>(
        Wtc, cT, up, 720, 512, 2048, 2048, 2048, 512,
        0, 0, 1048576, 0, 368640, 0, btc, 0, nullptr, 0, 1, nullptr, 1.0f, 0);

    // out = up * Woc^T + bo (per-col); dtype per probed flag; 360 blocks
    gemm_bt<64, 64><<<dim3(8, 45, 1), 256, 0, stream>>>(
        up, Woc, d_out, 2880, 512, 512, 512, 512, 512,
        0, 0, 0, 0, 0, 0, nullptr, 0, boc, 0, 1, flag, 1.0f, 0);
}

// Round 6
// 190.660 us; speedup vs baseline: 1.0559x; 1.0272x over previous
//
#include <hip/hip_runtime.h>
#include <hip/hip_bf16.h>

// Model_3315714753203: B=4,S=2048,I=512,D=512,H=8,HD=64,P=720.
// fp32 inputs (probed in convert) -> internal bf16.
// 5 dispatches: convert(+inline probe, VECTORIZED r6) -> qkv2 (128x128) ->
// flash v11b -> GEMM up -> GEMM out. ALL GEMM LDS tiles XOR-chunk-swizzled.
// r6: (1) convert_all mode-0 paths vectorized: f32 input = 2x float4 loads +
// 8x cvt + 16B store; bf16 input = pure 16B copy (old path was scalar 4B
// loads ~2.4 TB/s; ~40MB traffic -> est 17us -> ~7us). mode-1 transposed
// weights (3x512KB, L2-absorbed) stay scalar. (2) flash: voffk[4] array
// collapsed to voff0 ^ (kg*16) -- the swizzle (2kg+(lg>>1))^sw is XOR-linear
// in kg (2kg even, shift distributes over XOR; bits 4-5 of voff0 are exactly
// the swizzle term) -- 3 fewer live VGPRs to shrink the ~8-reg one-time
// spill (WRITE 16.4 vs 8.4MB ideal). flash structure otherwise = v11 exact.

typedef short bf16x8 __attribute__((ext_vector_type(8)));
typedef short short4v __attribute__((ext_vector_type(4)));
typedef float f32x4 __attribute__((ext_vector_type(4)));
typedef const __attribute__((address_space(1))) void* gptr_t;
typedef __attribute__((address_space(3))) void* sptr_t;

__device__ __forceinline__ f32x4 mfma16(bf16x8 a, bf16x8 b, f32x4 c) {
    return __builtin_amdgcn_mfma_f32_16x16x32_bf16(a, b, c, 0, 0, 0);
}
__device__ __forceinline__ f32x4 mfma16k(short4v a, short4v b, f32x4 c) {
#if __has_builtin(__builtin_amdgcn_mfma_f32_16x16x16bf16_1k)
    return __builtin_amdgcn_mfma_f32_16x16x16bf16_1k(a, b, c, 0, 0, 0);
#else
    (void)a; (void)b; return c;   // host-pass stub
#endif
}
__device__ __forceinline__ void async16(const void* g, void* l) {
    __builtin_amdgcn_global_load_lds((gptr_t)g, (sptr_t)l, 16, 0, 0);
}
// raw v_exp_f32 (OCML exp2f adds ~6 insts of fixup we don't need: scores bounded)
__device__ __forceinline__ float fexp2(float x) {
#if __has_builtin(__builtin_amdgcn_exp2f)
    return __builtin_amdgcn_exp2f(x);
#else
    return exp2f(x);
#endif
}
// pack 4 f32 -> 4 bf16 (round-half-up: +0x8000, take high 16)
__device__ __forceinline__ short4v pack_bf16x4(f32x4 v) {
    unsigned a = __builtin_bit_cast(unsigned, v[0]) + 0x8000u;
    unsigned b = __builtin_bit_cast(unsigned, v[1]) + 0x8000u;
    unsigned c = __builtin_bit_cast(unsigned, v[2]) + 0x8000u;
    unsigned d = __builtin_bit_cast(unsigned, v[3]) + 0x8000u;
    int2 t;
    t.x = (int)__builtin_amdgcn_perm(b, a, 0x07060302u);
    t.y = (int)__builtin_amdgcn_perm(d, c, 0x07060302u);
    return __builtin_bit_cast(short4v, t);
}

// ---------------- convert all inputs to bf16, inline dtype probe
struct CDesc { const void* s; __hip_bfloat16* d; int n; int mode; };
struct CTab  { CDesc t[11]; };

__global__ void convert_all(CTab tab, const unsigned* __restrict__ x0,
                            int* __restrict__ flag) {
    __shared__ int sflag;
    if (threadIdx.x < 64) {
        unsigned e = (x0[threadIdx.x] >> 23) & 0xffu;
        unsigned long long m = __ballot(e >= 100u && e <= 145u);
        if (threadIdx.x == 0) sflag = (__popcll(m) >= 32) ? 1 : 0;
    }
    __syncthreads();
    const int isF32 = sflag;
    if (blockIdx.x == 0 && blockIdx.y == 0 && threadIdx.x == 0) *flag = isF32;

    CDesc de = tab.t[blockIdx.y];
    if (de.mode) {
        // transposed weights: dst [h][d][i512] <- src [h][i512][d]; small
        // (262144 elems each, src re-reads L2-absorbed) -> scalar is fine.
        for (int i = blockIdx.x * 256 + threadIdx.x; i < de.n;
             i += gridDim.x * 256) {
            int ii = i & 511, d = (i >> 9) & 63, h = i >> 15;
            int si = (h * 512 + ii) * 64 + d;
            float v = isF32 ? ((const float*)de.s)[si]
                            : (float)((const __hip_bfloat16*)de.s)[si];
            de.d[i] = __float2bfloat16(v);
        }
    } else {
        // linear: every mode-0 n is divisible by 8 -> 16B-granular.
        const int nv = de.n >> 3;
        if (isF32) {
            const float4* s4 = (const float4*)de.s;
            for (int i = blockIdx.x * 256 + threadIdx.x; i < nv;
                 i += gridDim.x * 256) {
                float4 a = s4[i * 2], b = s4[i * 2 + 1];
                union { __hip_bfloat16 h[8]; int4 v; } u;
                u.h[0] = __float2bfloat16(a.x);
                u.h[1] = __float2bfloat16(a.y);
                u.h[2] = __float2bfloat16(a.z);
                u.h[3] = __float2bfloat16(a.w);
                u.h[4] = __float2bfloat16(b.x);
                u.h[5] = __float2bfloat16(b.y);
                u.h[6] = __float2bfloat16(b.z);
                u.h[7] = __float2bfloat16(b.w);
                *(int4*)&de.d[i * 8] = u.v;
            }
        } else {
            // already bf16: old path was bf16->f32->bf16 (identity) -> copy.
            const int4* s4 = (const int4*)de.s;
            for (int i = blockIdx.x * 256 + threadIdx.x; i < nv;
                 i += gridDim.x * 256)
                *(int4*)&de.d[i * 8] = s4[i];
        }
    }
}

// ---------------- generic GEMM core (K=512), XOR-swizzled LDS tiles,
// epilogue via functor (val, row, col). BM=BN=128: FM=FN=4, 16 MFMA/ks.
template<int BM, int BN, class EPI>
__device__ __forceinline__ void gemm_core(
    const __hip_bfloat16* __restrict__ A,
    const __hip_bfloat16* __restrict__ B,
    int lda, int ldb, int M, int N, int m0, int n0,
    __hip_bfloat16* lA, __hip_bfloat16* lB, EPI epi)
{
    constexpr int FM = BM / 32, FN = BN / 32;
    const int tid = threadIdx.x, lane = tid & 63, wave = tid >> 6;
    const int wm = (wave >> 1) * (BM / 2), wn = (wave & 1) * (BN / 2);
    const int lc = lane & 15, lg = lane >> 4;

    f32x4 acc[FM][FN] = {};
    constexpr int CA = BM * 8 / 256, CB = BN * 8 / 256;

    for (int k0 = 0; k0 < 512; k0 += 64) {
        #pragma unroll
        for (int j = 0; j < CA; ++j) {
            int ch = j * 256 + tid;
            int m = ch >> 3, kc = (ch & 7) ^ (m & 7);
            int mg = m0 + m; if (mg > M - 1) mg = M - 1;
            async16(&A[(size_t)mg * lda + k0 + kc * 8], &lA[ch * 8]);
        }
        #pragma unroll
        for (int j = 0; j < CB; ++j) {
            int ch = j * 256 + tid;
            int n = ch >> 3, kc = (ch & 7) ^ (n & 7);
            int ng = n0 + n; if (ng > N - 1) ng = N - 1;
            async16(&B[(size_t)ng * ldb + k0 + kc * 8], &lB[ch * 8]);
        }
        __syncthreads();
        #pragma unroll
        for (int ks = 0; ks < 64; ks += 32) {
            bf16x8 af[FM], bfr[FN];
            #pragma unroll
            for (int i = 0; i < FM; ++i) {
                int row = wm + i * 16 + lc;
                af[i] = *(const bf16x8*)&lA[row * 64 + (((ks >> 3) + lg) ^ (row & 7)) * 8];
            }
            #pragma unroll
            for (int j = 0; j < FN; ++j) {
                int row = wn + j * 16 + lc;
                bfr[j] = *(const bf16x8*)&lB[row * 64 + (((ks >> 3) + lg) ^ (row & 7)) * 8];
            }
            #pragma unroll
            for (int i = 0; i < FM; ++i)
                #pragma unroll
                for (int j = 0; j < FN; ++j)
                    acc[i][j] = mfma16(af[i], bfr[j], acc[i][j]);
        }
        __syncthreads();
    }
    #pragma unroll
    for (int i = 0; i < FM; ++i) {
        int rbase = m0 + wm + i * 16 + lg * 4;
        #pragma unroll
        for (int j = 0; j < FN; ++j) {
            int col = n0 + wn + j * 16 + lc;
            #pragma unroll
            for (int r = 0; r < 4; ++r)
                epi(acc[i][j][r], rbase + r, col);
        }
    }
}

// ---------------- qkv2: 128x128-tile merged projections.
// bid<512: q|k GEMM M=8192(b,s) N=1024(head-d; 0..511=q, 512..1023=k) K=512.
//   Wqk rows (h*64+d) contiguous (WqT then WkT in ws); bqk likewise.
//   Epilogue scatters to q/kk [h*4+b][s][64] and scales q cols by qscale.
// bid>=512: v GEMM M=512(h,d) N=2048(s) K=512, per batch b.
//   Epilogue scatters to vT [h*4+b][64][2048] (+bv per row).
__global__ __launch_bounds__(256, 2) void qkv_gemm(
    const __hip_bfloat16* __restrict__ Xc,
    const __hip_bfloat16* __restrict__ WqkT,
    const __hip_bfloat16* __restrict__ WvT,
    __hip_bfloat16* __restrict__ qk,
    __hip_bfloat16* __restrict__ vTo,
    const __hip_bfloat16* __restrict__ bqk,
    const __hip_bfloat16* __restrict__ bv,
    float qscale)
{
    __shared__ __align__(16) __hip_bfloat16 smem[2 * 128 * 64];
    const int bid = blockIdx.x;
    if (bid < 512) {
        const int m0 = (bid & 63) * 128, n0 = (bid >> 6) * 128;
        gemm_core<128, 128>(
            Xc, WqkT, 512, 512, 8192, 1024, m0, n0,
            smem, smem + 128 * 64,
            [&](float v, int row, int col) {
                v += (float)bqk[col];
                if (col < 512) v *= qscale;
                int hd = col & 511, hh = hd >> 6, d = hd & 63;
                int bb = row >> 11, s = row & 2047;
                size_t off = (size_t)(col >> 9) * 4194304 +
                             (size_t)(hh * 4 + bb) * 131072 + s * 64 + d;
                qk[off] = __float2bfloat16(v);
            });
    } else {
        const int t = bid - 512;
        const int bb = t >> 6, r = t & 63;
        const int m0 = (r >> 4) * 128, n0 = (r & 15) * 128;
        gemm_core<128, 128>(
            WvT, Xc + (size_t)bb * 1048576, 512, 512, 512, 2048, m0, n0,
            smem, smem + 128 * 64,
            [&](float v, int row, int col) {
                v += (float)bv[row];
                int hh = row >> 6, d = row & 63;
                size_t off = (size_t)hh * 524288 + (size_t)bb * 131072 +
                             d * 2048 + col;
                vTo[off] = __float2bfloat16(v);
            });
    }
}

// ---------------- generic MFMA GEMM (up/out), XOR-swizzled LDS
template<int BM, int BN>
__global__ __launch_bounds__(256, 2) void gemm_bt(
    const __hip_bfloat16* __restrict__ A,
    const __hip_bfloat16* __restrict__ B,
    void* __restrict__ C,
    int M, int N, int K, int lda, int ldb, int ldc,
    long sA1, long sA0, long sB1, long sB0, long sC1, long sC0,
    const __hip_bfloat16* __restrict__ biasM, long sbM1,
    const __hip_bfloat16* __restrict__ biasN, long sbN1,
    int Z0, const int* __restrict__ outF32flag, float cscale, int scaleZmax)
{
    constexpr int BK = 64;
    const int z = blockIdx.z;
    const int z1 = z / Z0, z0 = z - z1 * Z0;
    A += (size_t)z1 * sA1 + (size_t)z0 * sA0;
    B += (size_t)z1 * sB1 + (size_t)z0 * sB0;
    const size_t cbase = (size_t)z1 * sC1 + (size_t)z0 * sC0;
    if (biasM) biasM += (size_t)z1 * sbM1;
    if (biasN) biasN += (size_t)z1 * sbN1;
    const int outF32 = outF32flag ? *outF32flag : 0;
    const float csc = (z1 < scaleZmax) ? cscale : 1.0f;

    __shared__ __align__(16) __hip_bfloat16 lA[BM * BK];
    __shared__ __align__(16) __hip_bfloat16 lB[BN * BK];
    const int tid = threadIdx.x, lane = tid & 63, wave = tid >> 6;
    const int m0 = blockIdx.y * BM, n0 = blockIdx.x * BN;
    constexpr int WM = BM / 2, WN = BN / 2, FM = WM / 16, FN = WN / 16;
    const int wm = (wave >> 1) * WM, wn = (wave & 1) * WN;
    const int lc = lane & 15, lg = lane >> 4;

    f32x4 acc[FM][FN] = {};
    constexpr int CA = BM * 8 / 256, CB = BN * 8 / 256;

    for (int k0 = 0; k0 < K; k0 += BK) {
        #pragma unroll
        for (int j = 0; j < CA; ++j) {
            int ch = j * 256 + tid;
            int m = ch >> 3, kc = (ch & 7) ^ (m & 7);
            int mg = m0 + m; if (mg > M - 1) mg = M - 1;
            async16(&A[(size_t)mg * lda + k0 + kc * 8], &lA[ch * 8]);
        }
        #pragma unroll
        for (int j = 0; j < CB; ++j) {
            int ch = j * 256 + tid;
            int n = ch >> 3, kc = (ch & 7) ^ (n & 7);
            int ng = n0 + n; if (ng > N - 1) ng = N - 1;
            async16(&B[(size_t)ng * ldb + k0 + kc * 8], &lB[ch * 8]);
        }
        __syncthreads();
        #pragma unroll
        for (int ks = 0; ks < BK; ks += 32) {
            bf16x8 af[FM], bfr[FN];
            #pragma unroll
            for (int i = 0; i < FM; ++i) {
                int row = wm + i * 16 + lc;
                af[i] = *(const bf16x8*)&lA[row * 64 + (((ks >> 3) + lg) ^ (row & 7)) * 8];
            }
            #pragma unroll
            for (int j = 0; j < FN; ++j) {
                int row = wn + j * 16 + lc;
                bfr[j] = *(const bf16x8*)&lB[row * 64 + (((ks >> 3) + lg) ^ (row & 7)) * 8];
            }
            #pragma unroll
            for (int i = 0; i < FM; ++i)
                #pragma unroll
                for (int j = 0; j < FN; ++j)
                    acc[i][j] = mfma16(af[i], bfr[j], acc[i][j]);
        }
        __syncthreads();
    }
    #pragma unroll
    for (int i = 0; i < FM; ++i) {
        int rbase = m0 + wm + i * 16 + lg * 4;
        #pragma unroll
        for (int j = 0; j < FN; ++j) {
            int col = n0 + wn + j * 16 + lc;
            if (col >= N) continue;
            float bn = biasN ? (float)biasN[col] : 0.0f;
            #pragma unroll
            for (int r = 0; r < 4; ++r) {
                int row = rbase + r;
                if (row < M) {
                    float v = acc[i][j][r] + bn;
                    if (biasM) v += (float)biasM[row];
                    v *= csc;
                    size_t idx = cbase + (size_t)row * ldc + col;
                    if (outF32) ((float*)C)[idx] = v;
                    else ((__hip_bfloat16*)C)[idx] = __float2bfloat16(v);
                }
            }
        }
    }
}

// ---------------- flash attention v11b: 512-thread blocks, 8 waves =
// 4 q-subtiles (32 rows each) x 2 t-parity groups. Group g processes tiles
// t = g, g+2, ..., g+30 using its own LDS double-buffer pair (64KB total).
// No running max (scores bounded, qscale=log2e/64 in q) -> t-split exact;
// partials combined through LDS at the end. v11b: voffk array -> voff0 ^
// (kg*16) literal XOR (swizzle is XOR-linear in kg; 3 fewer live VGPRs).
// q,k: [H*B][S][64]; vT: [H*B][64][S]; out cT: [B][512][S]
__global__ __launch_bounds__(512, 4) void flash_attn(
    const __hip_bfloat16* __restrict__ q,
    const __hip_bfloat16* __restrict__ k,
    const __hip_bfloat16* __restrict__ vT,
    __hip_bfloat16* __restrict__ cT)
{
    const int S = 2048;
    const int h = blockIdx.y >> 2, b = blockIdx.y & 3;
    const int tid = threadIdx.x, lane = tid & 63;
    const int qw = (tid >> 6) & 3;     // q sub-tile (32 rows) within block
    const int grp = tid >> 8;          // t-parity group: 0 = even tiles, 1 = odd
    const int lc = lane & 15, lg = lane >> 4;
    const int s0 = blockIdx.x * 128 + qw * 32;

    const __hip_bfloat16* qb = q  + (size_t)(h * 4 + b) * S * 64;
    const __hip_bfloat16* kb = k  + (size_t)(h * 4 + b) * S * 64;
    const __hip_bfloat16* vb = vT + (size_t)(h * 4 + b) * 64 * S;

    // 64KB: buffer b in [b*8192, b*8192+8191]: K tile 4096 elems, V tile 4096.
    // group g owns buffers {g, g+2} -> bases g*8192 + {0, 16384}.
    __shared__ __align__(16) __hip_bfloat16 smem[32768];
    const int gbase = grp * 8192;

    bf16x8 qf[2][2];
    #pragma unroll
    for (int f = 0; f < 2; ++f)
        #pragma unroll
        for (int hh = 0; hh < 2; ++hh)
            qf[f][hh] = *(const bf16x8*)&qb[(size_t)(s0 + f * 16 + lc) * 64 + hh * 32 + lg * 8];

    // lane-constant offset BASES (elements); kg/dt walk via literal offsets.
    // swizzle sw = (row&7) = (lc&7) for every row=...*16+lc (16 == 0 mod 8).
    // K group index for hh=1 is (lg+4)^sw = (lg^sw)^4 -> koff1 = koff0 ^ 32.
    // V: (2kg+(lg>>1))^sw == ((lg>>1)^sw)^(2kg) (2kg even), and <<3
    // distributes over XOR -> voffk[kg] = voff0 ^ (kg*16).
    const int sw = lc & 7;
    const int koff0 = gbase + lc * 64 + ((lg ^ sw)) * 8;             // +kg*1024
    const int koff1 = koff0 ^ 32;                                    // +kg*1024
    const int voff0 = gbase + 4096 + lc * 64 +
                      (((lg >> 1) ^ sw) << 3) + (lg & 1) * 4;        // ^(kg*16)+dt*1024

    // staging offsets: each group (256 threads) stages its own 16KB tile;
    // 2 K-chunks + 2 V-chunks per thread, XOR-swizzled like the GEMMs.
    // chunk ch+256: row+32 == row (mod 8) -> same swizzle -> j=1 offsets are
    // j=0 + {2048 lds, 2048 K-elems, 32*S V-elems}.
    const int tidg = tid & 255;
    const int srow = tidg >> 3, scg = (tidg & 7) ^ (srow & 7);
    const int sld = gbase + tidg * 8;            // LDS K dest; V dest +4096
    const int kgo = srow * 64 + scg * 8;
    const size_t vgo = (size_t)srow * S + scg * 8;

    // prologue: group g stages its first tile (t = g) into its cur=0 buffer
    {
        const size_t kt = (size_t)grp * 4096, vt = (size_t)grp * 64;
        async16(&kb[kt + kgo],        &smem[sld]);
        async16(&kb[kt + kgo + 2048], &smem[sld + 2048]);
        async16(&vb[vgo + vt],         &smem[sld + 4096]);
        async16(&vb[vgo + vt + 65536], &smem[sld + 6144]);
    }
    __syncthreads();

    f32x4 O[2][4] = {};
    float lsum[2] = {0.0f, 0.0f};

    auto step = [&](int i, int cur) {
        if (i < 15) {  // prefetch this group's tile t+2 into the other buffer
            const int tn = grp + 2 * i + 2;
            const int nxt = cur ^ 16384;
            const size_t kt = (size_t)tn * 4096, vt = (size_t)tn * 64;
            async16(&kb[kt + kgo],        &smem[sld + nxt]);
            async16(&kb[kt + kgo + 2048], &smem[sld + nxt + 2048]);
            async16(&vb[vgo + vt],         &smem[sld + nxt + 4096]);
            async16(&vb[vgo + vt + 65536], &smem[sld + nxt + 6144]);
        }
        __builtin_amdgcn_s_setprio(1);
        #pragma unroll
        for (int kg = 0; kg < 4; ++kg) {
            bf16x8 kf0 = *(const bf16x8*)&smem[cur + koff0 + kg * 1024];
            bf16x8 kf1 = *(const bf16x8*)&smem[cur + koff1 + kg * 1024];
            short4v pb0, pb1;
            {
                f32x4 s = {};
                s = mfma16(kf0, qf[0][0], s);
                s = mfma16(kf1, qf[0][1], s);
                f32x4 e;
                #pragma unroll
                for (int r = 0; r < 4; ++r) e[r] = fexp2(s[r]);
                lsum[0] += (e[0] + e[1]) + (e[2] + e[3]);
                pb0 = pack_bf16x4(e);
            }
            {
                f32x4 s = {};
                s = mfma16(kf0, qf[1][0], s);
                s = mfma16(kf1, qf[1][1], s);
                f32x4 e;
                #pragma unroll
                for (int r = 0; r < 4; ++r) e[r] = fexp2(s[r]);
                lsum[1] += (e[0] + e[1]) + (e[2] + e[3]);
                pb1 = pack_bf16x4(e);
            }
            #pragma unroll
            for (int dt = 0; dt < 4; ++dt) {
                short4v vf = *(const short4v*)&smem[cur + (voff0 ^ (kg * 16)) + dt * 1024];
                O[0][dt] = mfma16k(vf, pb0, O[0][dt]);
                O[1][dt] = mfma16k(vf, pb1, O[1][dt]);
            }
        }
        __builtin_amdgcn_s_setprio(0);
        __syncthreads();
    };

    for (int i = 0; i < 16; i += 2) {
        step(i, 0);
        step(i + 1, 16384);
    }

    // ---- combine the two t-halves through LDS (buffers dead after last barrier)
    // grp1 partials: O at f32[0..8191] (32KB), lsum at f32[8192..8703] (2KB)
    float* pf = (float*)smem;
    if (grp == 1) {
        #pragma unroll
        for (int f = 0; f < 2; ++f) {
            #pragma unroll
            for (int dt = 0; dt < 4; ++dt) {
                int base = (((qw * 2 + f) * 4 + dt) * 4) * 64 + lane;
                #pragma unroll
                for (int r = 0; r < 4; ++r) pf[base + r * 64] = O[f][dt][r];
            }
            pf[8192 + (qw * 2 + f) * 64 + lane] = lsum[f];
        }
    }
    __syncthreads();
    __hip_bfloat16* tb = &smem[20480];   // transpose buffer [64][136], disjoint from pf
    if (grp == 0) {
        float inv[2];
        #pragma unroll
        for (int f = 0; f < 2; ++f) {
            #pragma unroll
            for (int dt = 0; dt < 4; ++dt) {
                int base = (((qw * 2 + f) * 4 + dt) * 4) * 64 + lane;
                #pragma unroll
                for (int r = 0; r < 4; ++r) O[f][dt][r] += pf[base + r * 64];
            }
            float v = lsum[f] + pf[8192 + (qw * 2 + f) * 64 + lane];
            v += __shfl_xor(v, 16);
            v += __shfl_xor(v, 32);
            inv[f] = 1.0f / v;
        }
        #pragma unroll
        for (int f = 0; f < 2; ++f)
            #pragma unroll
            for (int dt = 0; dt < 4; ++dt)
                #pragma unroll
                for (int r = 0; r < 4; ++r)
                    tb[(dt * 16 + lg * 4 + r) * 136 + qw * 32 + f * 16 + lc] =
                        __float2bfloat16(O[f][dt][r] * inv[f]);
    }
    __syncthreads();
    int row = tid >> 3, c0 = (tid & 7) * 16;
    size_t off = ((size_t)b * 512 + h * 64 + row) * S + blockIdx.x * 128 + c0;
    #pragma unroll
    for (int cc = 0; cc < 2; ++cc)
        *(bf16x8*)&cT[off + cc * 8] = *(const bf16x8*)&tb[row * 136 + c0 + cc * 8];
}

extern "C" void kernel_launch(void* const* d_in, const int* in_sizes, int n_in,
                              void* d_out, int out_size, void* d_ws, size_t ws_size,
                              hipStream_t stream) {
    using bf = __hip_bfloat16;
    bf* ws = (bf*)d_ws;
    int* flag = (int*)d_ws;
    bf* bqc = ws + 64;         // bqc[512] then bkc[512] contiguous = bqk[1024]
    bf* bkc = ws + 576;
    bf* bvc = ws + 1088;
    bf* btc = ws + 1600;
    bf* boc = ws + 2320;
    bf* WqT = ws + 4096;       // [8][64][512]; WkT contiguous after = Wqk[1024][512]
    bf* WkT = ws + 266240;
    bf* WvT = ws + 528384;
    bf* Wtc = ws + 790528;     // [720][2048]
    bf* Woc = ws + 2265088;    // [512][512]
    bf* Xc  = ws + 2527232;    // [4][2048][512], dead after qkv gemm
    bf* cT  = ws + 2527232;    // [4][512][2048], overlays Xc
    bf* q   = ws + 6721536;    // [32][2048][64]; kk contiguous after (+4194304)
    bf* up  = ws + 6721536;    // [4][720][512], overlays q after flash
    bf* kk  = ws + 10915840;   // [32][2048][64]
    bf* vT  = ws + 15110144;   // [32][64][2048]

    CTab tab;
    tab.t[0]  = { d_in[0],  Xc,  4194304, 0 };
    tab.t[1]  = { d_in[1],  WqT, 262144,  1 };
    tab.t[2]  = { d_in[2],  bqc, 512,     0 };
    tab.t[3]  = { d_in[3],  WkT, 262144,  1 };
    tab.t[4]  = { d_in[4],  bkc, 512,     0 };
    tab.t[5]  = { d_in[5],  WvT, 262144,  1 };
    tab.t[6]  = { d_in[6],  bvc, 512,     0 };
    tab.t[7]  = { d_in[7],  Wtc, 1474560, 0 };
    tab.t[8]  = { d_in[8],  btc, 720,     0 };
    tab.t[9]  = { d_in[9],  Woc, 262144,  0 };
    tab.t[10] = { d_in[10], boc, 512,     0 };
    convert_all<<<dim3(512, 11), 256, 0, stream>>>(tab, (const unsigned*)d_in[0], flag);

    const float qscale = 0.022542110013890054f;  // log2(e)/64
    qkv_gemm<<<dim3(768), 256, 0, stream>>>(Xc, WqT, WvT, q, vT, bqc, bvc, qscale);

    flash_attn<<<dim3(16, 32), 512, 0, stream>>>(q, kk, vT, cT);

    // up[b] = Wt * cT[b]^T + bt (per-row)  (z1=b); 384 blocks
    gemm_bt<64, 64><<<dim3(8, 12, 4), 256, 0, stream>>>(
        Wtc, cT, up, 720, 512, 2048, 2048, 2048, 512,
        0, 0, 1048576, 0, 368640, 0, btc, 0, nullptr, 0, 1, nullptr, 1.0f, 0);

    // out = up * Woc^T + bo (per-col); dtype per probed flag; 360 blocks
    gemm_bt<64, 64><<<dim3(8, 45, 1), 256, 0, stream>>>(
        up, Woc, d_out, 2880, 512, 512, 512, 512, 512,
        0, 0, 0, 0, 0, 0, nullptr, 0, boc, 0, 1, flag, 1.0f, 0);
}